// Round 1
// baseline (323.602 us; speedup 1.0000x reference)
//
#include <hip/hip_runtime.h>
#include <hip/hip_cooperative_groups.h>
#include <math.h>

namespace cg = cooperative_groups;

#define B_ROWS 4096
#define D_DIM  2048
#define NBLK   1024
#define ROWS_PER_BLK (B_ROWS / NBLK)   // 4
#define MARGIN_F 0.05f
#define HUBER_DELTA_F 0.1f
#define COS_EPS_F 1e-8f

// Single fused cooperative kernel.
// Phase 1: one wave per row -> cosine sim + overall + huber partial (register-only
//          butterfly reduce; no LDS, no __syncthreads).
// grid.sync()
// Phase 2: pair loss. Each block owns 4 i-rows (the same ones it computed), j-scans
//          sim/overall straight from global (L2-hot; each j read once per block and
//          reused across 4 i-rows in registers -- LDS staging would be pure overhead
//          here and would cap occupancy below the cooperative-residency requirement).
//          Partials to unique slots; NO same-address atomics (R2: serialized @L2).
// grid.sync()
// Phase 3: block 0 reduces the 1024 partials and writes the 3 outputs.
__global__ __launch_bounds__(256, 4) void fused_kernel(
    const float* __restrict__ z_ref, const float* __restrict__ z_perf,
    const float* __restrict__ pred, const float* __restrict__ tgt,
    float* __restrict__ sim, float* __restrict__ overall,
    float* __restrict__ pair_part, float* __restrict__ hub_part,
    unsigned int* __restrict__ cnt_part, float* __restrict__ out)
{
    __shared__ float hubw[4];
    __shared__ float pw[4];
    __shared__ float hw[4];
    __shared__ unsigned int cw[4];

    const int tid  = threadIdx.x;
    const int lane = tid & 63;
    const int wave = tid >> 6;
    const int bid  = blockIdx.x;

    // ---------------- Phase 1: wave-per-row cosine + huber ----------------
    {
        const int row = bid * ROWS_PER_BLK + wave;
        const float4* a4 = (const float4*)(z_ref + (size_t)row * D_DIM);
        const float4* b4 = (const float4*)(z_perf + (size_t)row * D_DIM);
        float dot = 0.f, na2 = 0.f, nb2 = 0.f;
        #pragma unroll
        for (int k = 0; k < 8; ++k) {          // 512 float4 per row / 64 lanes
            float4 a = a4[lane + k * 64];
            float4 b = b4[lane + k * 64];
            dot += a.x*b.x + a.y*b.y + a.z*b.z + a.w*b.w;
            na2 += a.x*a.x + a.y*a.y + a.z*a.z + a.w*a.w;
            nb2 += b.x*b.x + b.y*b.y + b.z*b.z + b.w*b.w;
        }
        #pragma unroll
        for (int off = 32; off > 0; off >>= 1) {
            dot += __shfl_down(dot, off, 64);
            na2 += __shfl_down(na2, off, 64);
            nb2 += __shfl_down(nb2, off, 64);
        }
        // Huber partials for this row's 4 score elements on lanes 0..3
        float hub = 0.f;
        if (lane < 4) {
            float d  = pred[row * 4 + lane] - tgt[row * 5 + lane];
            float ad = fabsf(d);
            hub = (ad <= HUBER_DELTA_F) ? 0.5f * d * d
                                        : HUBER_DELTA_F * (ad - 0.5f * HUBER_DELTA_F);
        }
        hub += __shfl_down(hub, 2, 64);
        hub += __shfl_down(hub, 1, 64);
        if (lane == 0) {
            float na = fmaxf(sqrtf(na2), COS_EPS_F);
            float nb = fmaxf(sqrtf(nb2), COS_EPS_F);
            sim[row]     = dot / (na * nb);
            overall[row] = tgt[row * 5 + 4];
            hubw[wave]   = hub;
        }
    }

    cg::this_grid().sync();   // all sim/overall visible grid-wide (incl. block barrier)

    // ---------------- Phase 2: pair loss, 4 i-rows per block ----------------
    {
        const int i0 = bid * ROWS_PER_BLK;
        float s_i[ROWS_PER_BLK], o_i[ROWS_PER_BLK];
        #pragma unroll
        for (int ii = 0; ii < ROWS_PER_BLK; ++ii) {
            s_i[ii] = sim[i0 + ii];
            o_i[ii] = overall[i0 + ii];
        }
        float part = 0.f;
        unsigned int cnt = 0;
        #pragma unroll 4
        for (int j = tid; j < B_ROWS; j += 256) {   // 16 iters, coalesced, L2-hot
            float sj = sim[j];
            float oj = overall[j];
            #pragma unroll
            for (int ii = 0; ii < ROWS_PER_BLK; ++ii) {
                if (o_i[ii] > oj) {
                    part += fmaxf(sj - s_i[ii] + MARGIN_F, 0.f);
                    cnt++;
                }
            }
        }
        #pragma unroll
        for (int off = 32; off > 0; off >>= 1) {
            part += __shfl_down(part, off, 64);
            cnt  += __shfl_down(cnt,  off, 64);
        }
        if (lane == 0) { pw[wave] = part; cw[wave] = cnt; }
        __syncthreads();
        if (tid == 0) {
            pair_part[bid] = pw[0] + pw[1] + pw[2] + pw[3];
            cnt_part[bid]  = cw[0] + cw[1] + cw[2] + cw[3];
            hub_part[bid]  = hubw[0] + hubw[1] + hubw[2] + hubw[3];
        }
    }

    cg::this_grid().sync();   // partials visible; also fences LDS reuse below

    // ---------------- Phase 3: block 0 reduces 1024 partials ----------------
    if (bid == 0) {
        float pr = 0.f, hb = 0.f;
        unsigned int cnt = 0;
        #pragma unroll
        for (int k = tid; k < NBLK; k += 256) {     // 4 iters
            pr  += pair_part[k];
            hb  += hub_part[k];
            cnt += cnt_part[k];
        }
        #pragma unroll
        for (int off = 32; off > 0; off >>= 1) {
            pr  += __shfl_down(pr,  off, 64);
            hb  += __shfl_down(hb,  off, 64);
            cnt += __shfl_down(cnt, off, 64);
        }
        if (lane == 0) { pw[wave] = pr; hw[wave] = hb; cw[wave] = cnt; }
        __syncthreads();
        if (tid == 0) {
            float P = pw[0] + pw[1] + pw[2] + pw[3];
            float H = hw[0] + hw[1] + hw[2] + hw[3];
            unsigned int C = cw[0] + cw[1] + cw[2] + cw[3];
            float n   = (float)C;
            float L_c = (n > 0.f) ? P / fmaxf(n, 1.f) : 0.f;
            float L_s = H / (float)(B_ROWS * 4);
            out[0] = L_c + L_s;
            out[1] = L_c;
            out[2] = L_s;
        }
    }
}

extern "C" void kernel_launch(void* const* d_in, const int* in_sizes, int n_in,
                              void* d_out, int out_size, void* d_ws, size_t ws_size,
                              hipStream_t stream) {
    const float* z_ref  = (const float*)d_in[0];
    const float* z_perf = (const float*)d_in[1];
    const float* pred   = (const float*)d_in[2];
    const float* tgt    = (const float*)d_in[3];
    float* out = (float*)d_out;

    // Workspace layout (floats), every slot written unconditionally each call:
    // [0,4096)=sim  [4096,8192)=overall  [8192,9216)=pair_part
    // [9216,10240)=hub_part  [10240,11264)=cnt_part (uint bits)
    float* ws        = (float*)d_ws;
    float* sim       = ws;
    float* overall   = ws + B_ROWS;
    float* pair_part = ws + 2 * B_ROWS;
    float* hub_part  = ws + 2 * B_ROWS + NBLK;
    unsigned int* cnt_part = (unsigned int*)(ws + 2 * B_ROWS + 2 * NBLK);

    void* args[] = { &z_ref, &z_perf, &pred, &tgt, &sim, &overall,
                     &pair_part, &hub_part, &cnt_part, &out };
    hipLaunchCooperativeKernel((const void*)fused_kernel, dim3(NBLK), dim3(256),
                               args, 0, stream);
}

// Round 2
// 121.534 us; speedup vs baseline: 2.6626x; 2.6626x over previous
//
#include <hip/hip_runtime.h>
#include <math.h>

#define B_ROWS 4096
#define D_DIM  2048
#define NBLK   1024
#define ROWS_PER_BLK (B_ROWS / NBLK)        // 4
#define MARGIN_F 0.05f
#define HUBER_DELTA_F 0.1f
#define COS_EPS_F 1e-8f

// Completion-tree geometry for the last-block-done merge of the finalize step.
// R1 lesson: grid-wide sync via cg::grid.sync() (atomic arrivals on ONE address +
// flag poll) cost ~200 us for 1024 blocks. Two-level tree on padded cache lines
// keeps worst-case serialization to ~16 atomics/line + 64 on the root.
#define NLEAF 64
#define LEAF_STRIDE 32                       // uints -> 128 B between counters
#define BLOCKS_PER_LEAF (NBLK / NLEAF)       // 16
#define ROOT_IDX (NLEAF * LEAF_STRIDE)       // counters[2048]

// Kernel A: pure streaming cosine. One wave per row (4 waves/block), register-only
// butterfly reduce -- no LDS, no __syncthreads. Block 0 also re-zeroes the
// completion counters (workspace is poisoned every call; stream order A->B
// guarantees visibility). Huber moved to kernel B (A stays pure BW).
__global__ __launch_bounds__(256) void sim_kernel(
    const float* __restrict__ z_ref, const float* __restrict__ z_perf,
    const float* __restrict__ tgt,
    float* __restrict__ sim, float* __restrict__ overall,
    unsigned int* __restrict__ counters)
{
    const int tid  = threadIdx.x;
    const int lane = tid & 63;
    const int wave = tid >> 6;
    const int bid  = blockIdx.x;

    if (bid == 0 && tid <= NLEAF) counters[tid * LEAF_STRIDE] = 0u;

    const int row = bid * ROWS_PER_BLK + wave;
    const float4* a4 = (const float4*)(z_ref + (size_t)row * D_DIM);
    const float4* b4 = (const float4*)(z_perf + (size_t)row * D_DIM);

    float dot = 0.f, na2 = 0.f, nb2 = 0.f;
    #pragma unroll
    for (int k = 0; k < 8; ++k) {            // 512 float4 per row / 64 lanes
        float4 a = a4[lane + k * 64];
        float4 b = b4[lane + k * 64];
        dot += a.x*b.x + a.y*b.y + a.z*b.z + a.w*b.w;
        na2 += a.x*a.x + a.y*a.y + a.z*a.z + a.w*a.w;
        nb2 += b.x*b.x + b.y*b.y + b.z*b.z + b.w*b.w;
    }
    #pragma unroll
    for (int off = 32; off > 0; off >>= 1) {
        dot += __shfl_down(dot, off, 64);
        na2 += __shfl_down(na2, off, 64);
        nb2 += __shfl_down(nb2, off, 64);
    }
    if (lane == 0) {
        float na = fmaxf(sqrtf(na2), COS_EPS_F);
        float nb = fmaxf(sqrtf(nb2), COS_EPS_F);
        sim[row]     = dot / (na * nb);
        overall[row] = tgt[row * 5 + 4];
    }
}

// Kernel B: pair loss + huber + (last block only) finalize.
// sim/overall staged in LDS once per block, each j-read reused across the block's
// 4 i-rows. Partials to unique slots. Completion tracked via the padded 2-level
// counter tree; the 1024th block to arrive reduces the 3x1024 partials and writes
// the outputs. No spin anywhere -> no deadlock risk, works under graph capture.
__global__ __launch_bounds__(256) void pair_kernel(
    const float* __restrict__ sim, const float* __restrict__ overall,
    const float* __restrict__ pred, const float* __restrict__ tgt,
    float* __restrict__ pair_part, float* __restrict__ hub_part,
    unsigned int* __restrict__ cnt_part, unsigned int* __restrict__ counters,
    float* __restrict__ out)
{
    __shared__ float ls[B_ROWS];
    __shared__ float lo[B_ROWS];
    __shared__ float pw[4], hw[4];
    __shared__ unsigned int cw[4];
    __shared__ int is_last;

    const int tid  = threadIdx.x;
    const int lane = tid & 63;
    const int wave = tid >> 6;
    const int bid  = blockIdx.x;

    // Stage sim/overall (32 KB) to LDS, vectorized.
    const float4* s4 = (const float4*)sim;
    const float4* o4 = (const float4*)overall;
    float4* ls4 = (float4*)ls;
    float4* lo4 = (float4*)lo;
    #pragma unroll
    for (int k = 0; k < (B_ROWS / 4) / 256; ++k) {   // 4 iters
        const int idx = tid + k * 256;
        ls4[idx] = s4[idx];
        lo4[idx] = o4[idx];
    }
    __syncthreads();

    const int i0 = bid * ROWS_PER_BLK;
    float s_i[ROWS_PER_BLK], o_i[ROWS_PER_BLK];
    #pragma unroll
    for (int ii = 0; ii < ROWS_PER_BLK; ++ii) {
        s_i[ii] = ls[i0 + ii];
        o_i[ii] = lo[i0 + ii];
    }

    float part = 0.f;
    unsigned int cnt = 0;
    for (int j = tid; j < B_ROWS; j += 256) {        // 16 iters
        float sj = ls[j];
        float oj = lo[j];
        #pragma unroll
        for (int ii = 0; ii < ROWS_PER_BLK; ++ii) {
            if (o_i[ii] > oj) {
                part += fmaxf(sj - s_i[ii] + MARGIN_F, 0.f);
                cnt++;
            }
        }
    }

    // Huber for this block's 4 rows (16 elements on threads 0..15).
    float hub = 0.f;
    if (tid < 16) {
        const int r = i0 + (tid >> 2);
        const int e = tid & 3;
        float d  = pred[r * 4 + e] - tgt[r * 5 + e];
        float ad = fabsf(d);
        hub = (ad <= HUBER_DELTA_F) ? 0.5f * d * d
                                    : HUBER_DELTA_F * (ad - 0.5f * HUBER_DELTA_F);
    }

    #pragma unroll
    for (int off = 32; off > 0; off >>= 1) {
        part += __shfl_down(part, off, 64);
        cnt  += __shfl_down(cnt,  off, 64);
        hub  += __shfl_down(hub,  off, 64);
    }
    if (lane == 0) { pw[wave] = part; cw[wave] = cnt; hw[wave] = hub; }
    __syncthreads();

    if (tid == 0) {
        pair_part[bid] = pw[0] + pw[1] + pw[2] + pw[3];
        cnt_part[bid]  = cw[0] + cw[1] + cw[2] + cw[3];
        hub_part[bid]  = hw[0] + hw[1] + hw[2] + hw[3];
        __threadfence();                              // release partials (device scope)
        is_last = 0;
        unsigned int l = atomicAdd(&counters[(bid & (NLEAF - 1)) * LEAF_STRIDE], 1u);
        if (l == BLOCKS_PER_LEAF - 1) {
            unsigned int r = atomicAdd(&counters[ROOT_IDX], 1u);
            if (r == NLEAF - 1) is_last = 1;
        }
    }
    __syncthreads();

    if (is_last) {
        __threadfence();                              // acquire side before reading partials
        float pr = 0.f, hb = 0.f;
        unsigned int c = 0;
        #pragma unroll
        for (int k = tid; k < NBLK; k += 256) {       // 4 iters
            pr += pair_part[k];
            hb += hub_part[k];
            c  += cnt_part[k];
        }
        #pragma unroll
        for (int off = 32; off > 0; off >>= 1) {
            pr += __shfl_down(pr, off, 64);
            hb += __shfl_down(hb, off, 64);
            c  += __shfl_down(c,  off, 64);
        }
        if (lane == 0) { pw[wave] = pr; hw[wave] = hb; cw[wave] = c; }
        __syncthreads();
        if (tid == 0) {
            float P = pw[0] + pw[1] + pw[2] + pw[3];
            float H = hw[0] + hw[1] + hw[2] + hw[3];
            unsigned int C = cw[0] + cw[1] + cw[2] + cw[3];
            float n   = (float)C;
            float L_c = (n > 0.f) ? P / fmaxf(n, 1.f) : 0.f;
            float L_s = H / (float)(B_ROWS * 4);
            out[0] = L_c + L_s;
            out[1] = L_c;
            out[2] = L_s;
        }
    }
}

extern "C" void kernel_launch(void* const* d_in, const int* in_sizes, int n_in,
                              void* d_out, int out_size, void* d_ws, size_t ws_size,
                              hipStream_t stream) {
    const float* z_ref  = (const float*)d_in[0];
    const float* z_perf = (const float*)d_in[1];
    const float* pred   = (const float*)d_in[2];
    const float* tgt    = (const float*)d_in[3];
    float* out = (float*)d_out;

    // Workspace layout (float offsets); every slot re-written each call:
    // [0,4096)        sim
    // [4096,8192)     overall
    // [8192,9216)     pair_part
    // [9216,10240)    hub_part
    // [10240,11264)   cnt_part   (uint bits)
    // [11264,13345)   counters   (uint bits; 64 leaves @ stride 32 + root)
    float* ws        = (float*)d_ws;
    float* sim       = ws;
    float* overall   = ws + B_ROWS;
    float* pair_part = ws + 2 * B_ROWS;
    float* hub_part  = ws + 2 * B_ROWS + NBLK;
    unsigned int* cnt_part = (unsigned int*)(ws + 2 * B_ROWS + 2 * NBLK);
    unsigned int* counters = (unsigned int*)(ws + 2 * B_ROWS + 3 * NBLK);

    sim_kernel<<<NBLK, 256, 0, stream>>>(z_ref, z_perf, tgt, sim, overall, counters);
    pair_kernel<<<NBLK, 256, 0, stream>>>(sim, overall, pred, tgt,
                                          pair_part, hub_part, cnt_part, counters, out);
}

// Round 3
// 107.418 us; speedup vs baseline: 3.0125x; 1.1314x over previous
//
#include <hip/hip_runtime.h>
#include <math.h>

#define B_ROWS 4096
#define D_DIM  2048
#define NBLK_B 256
#define ROWS_PER_B (B_ROWS / NBLK_B)        // 16
#define MARGIN_F 0.05f
#define HUBER_DELTA_F 0.1f
#define COS_EPS_F 1e-8f

// R1/R2 lessons (do not regress):
//  - cg::grid.sync() on 1024 blocks  -> ~200 us (atomic arrivals + poll). NEVER.
//  - __threadfence() release + atomic completion tree -> ~15 us (device-scope
//    fence = per-XCD L2 writeback on MI355X). NEVER.
//  - Stream-ordered kernel boundaries are the CHEAPEST grid barrier here.

// Kernel A: pure streaming cosine. One block per row, vectorized float4 loads,
// wave shuffle + tiny LDS cross-wave reduce. No atomics.
__global__ __launch_bounds__(256) void sim_kernel(
    const float* __restrict__ z_ref, const float* __restrict__ z_perf,
    const float* __restrict__ tgt,
    float* __restrict__ sim, float* __restrict__ overall)
{
    const int row = blockIdx.x;
    const int tid = threadIdx.x;
    const float4* a4 = (const float4*)(z_ref + (size_t)row * D_DIM);
    const float4* b4 = (const float4*)(z_perf + (size_t)row * D_DIM);

    float dot = 0.f, na2 = 0.f, nb2 = 0.f;
    #pragma unroll
    for (int k = 0; k < 2; ++k) {            // 512 float4 per row / 256 threads
        const int idx = tid + k * 256;
        float4 a = a4[idx];
        float4 b = b4[idx];
        dot += a.x*b.x + a.y*b.y + a.z*b.z + a.w*b.w;
        na2 += a.x*a.x + a.y*a.y + a.z*a.z + a.w*a.w;
        nb2 += b.x*b.x + b.y*b.y + b.z*b.z + b.w*b.w;
    }

    const int lane = tid & 63, wave = tid >> 6;
    #pragma unroll
    for (int off = 32; off > 0; off >>= 1) {
        dot += __shfl_down(dot, off, 64);
        na2 += __shfl_down(na2, off, 64);
        nb2 += __shfl_down(nb2, off, 64);
    }
    __shared__ float shm[3][4];
    if (lane == 0) { shm[0][wave] = dot; shm[1][wave] = na2; shm[2][wave] = nb2; }
    __syncthreads();
    if (tid == 0) {
        float dt = shm[0][0] + shm[0][1] + shm[0][2] + shm[0][3];
        float na = fmaxf(sqrtf(shm[1][0] + shm[1][1] + shm[1][2] + shm[1][3]), COS_EPS_F);
        float nb = fmaxf(sqrtf(shm[2][0] + shm[2][1] + shm[2][2] + shm[2][3]), COS_EPS_F);
        sim[row]     = dt / (na * nb);
        overall[row] = tgt[row * 5 + 4];
    }
}

// Kernel B: pair loss + huber. 256 blocks x 16 i-rows. sim/overall staged in LDS
// once per block (32 KB, vectorized, L2/L3-hot after A); each j-read reused
// across 16 i-rows held in registers. Huber for this block's 16 rows folded in
// (threads 0..63, one element each). Partials to unique slots -- no atomics.
__global__ __launch_bounds__(256) void pair_kernel(
    const float* __restrict__ sim, const float* __restrict__ overall,
    const float* __restrict__ pred, const float* __restrict__ tgt,
    float* __restrict__ pair_part, float* __restrict__ hub_part,
    unsigned int* __restrict__ cnt_part)
{
    __shared__ float ls[B_ROWS];
    __shared__ float lo[B_ROWS];
    __shared__ float pw[4], hw[4];
    __shared__ unsigned int cw[4];

    const int tid = threadIdx.x;

    const float4* s4 = (const float4*)sim;
    const float4* o4 = (const float4*)overall;
    float4* ls4 = (float4*)ls;
    float4* lo4 = (float4*)lo;
    #pragma unroll
    for (int k = 0; k < (B_ROWS / 4) / 256; ++k) {   // 4 iters
        const int idx = tid + k * 256;
        ls4[idx] = s4[idx];
        lo4[idx] = o4[idx];
    }

    // Huber while staging is in flight: 16 rows x 4 elems on threads 0..63.
    const int i0 = blockIdx.x * ROWS_PER_B;
    float hub = 0.f;
    if (tid < ROWS_PER_B * 4) {
        const int r = i0 + (tid >> 2);
        const int e = tid & 3;
        float d  = pred[r * 4 + e] - tgt[r * 5 + e];
        float ad = fabsf(d);
        hub = (ad <= HUBER_DELTA_F) ? 0.5f * d * d
                                    : HUBER_DELTA_F * (ad - 0.5f * HUBER_DELTA_F);
    }
    __syncthreads();

    float s_i[ROWS_PER_B], o_i[ROWS_PER_B];
    #pragma unroll
    for (int ii = 0; ii < ROWS_PER_B; ++ii) {        // LDS broadcast reads (free)
        s_i[ii] = ls[i0 + ii];
        o_i[ii] = lo[i0 + ii];
    }

    float part = 0.f;
    unsigned int cnt = 0;
    for (int j = tid; j < B_ROWS; j += 256) {        // 16 iters
        float sj = ls[j];
        float oj = lo[j];
        #pragma unroll
        for (int ii = 0; ii < ROWS_PER_B; ++ii) {
            if (o_i[ii] > oj) {
                part += fmaxf(sj - s_i[ii] + MARGIN_F, 0.f);
                cnt++;
            }
        }
    }

    const int lane = tid & 63, wave = tid >> 6;
    #pragma unroll
    for (int off = 32; off > 0; off >>= 1) {
        part += __shfl_down(part, off, 64);
        cnt  += __shfl_down(cnt,  off, 64);
        hub  += __shfl_down(hub,  off, 64);
    }
    if (lane == 0) { pw[wave] = part; cw[wave] = cnt; hw[wave] = hub; }
    __syncthreads();
    if (tid == 0) {
        pair_part[blockIdx.x] = pw[0] + pw[1] + pw[2] + pw[3];
        cnt_part[blockIdx.x]  = cw[0] + cw[1] + cw[2] + cw[3];
        hub_part[blockIdx.x]  = hw[0] + hw[1] + hw[2] + hw[3];
    }
}

// Kernel C: single block reduces 3 x 256 partials and writes the 3 outputs.
__global__ __launch_bounds__(256) void finalize_kernel(
    const float* __restrict__ hub_part, const float* __restrict__ pair_part,
    const unsigned int* __restrict__ cnt_part, float* __restrict__ out)
{
    const int tid = threadIdx.x;
    float hub = hub_part[tid];
    float pr  = pair_part[tid];
    unsigned int cnt = cnt_part[tid];

    const int lane = tid & 63, wave = tid >> 6;
    #pragma unroll
    for (int off = 32; off > 0; off >>= 1) {
        hub += __shfl_down(hub, off, 64);
        pr  += __shfl_down(pr,  off, 64);
        cnt += __shfl_down(cnt, off, 64);
    }
    __shared__ float hw[4], pw[4];
    __shared__ unsigned int cw[4];
    if (lane == 0) { hw[wave] = hub; pw[wave] = pr; cw[wave] = cnt; }
    __syncthreads();
    if (tid == 0) {
        float H = hw[0] + hw[1] + hw[2] + hw[3];
        float P = pw[0] + pw[1] + pw[2] + pw[3];
        unsigned int C = cw[0] + cw[1] + cw[2] + cw[3];
        float n   = (float)C;
        float L_c = (n > 0.f) ? P / fmaxf(n, 1.f) : 0.f;
        float L_s = H / (float)(B_ROWS * 4);
        out[0] = L_c + L_s;
        out[1] = L_c;
        out[2] = L_s;
    }
}

extern "C" void kernel_launch(void* const* d_in, const int* in_sizes, int n_in,
                              void* d_out, int out_size, void* d_ws, size_t ws_size,
                              hipStream_t stream) {
    const float* z_ref  = (const float*)d_in[0];
    const float* z_perf = (const float*)d_in[1];
    const float* pred   = (const float*)d_in[2];
    const float* tgt    = (const float*)d_in[3];
    float* out = (float*)d_out;

    // Workspace layout (float offsets); every slot re-written each call:
    // [0,4096)      sim
    // [4096,8192)   overall
    // [8192,8448)   pair_part
    // [8448,8704)   hub_part
    // [8704,8960)   cnt_part (uint bits)
    float* ws        = (float*)d_ws;
    float* sim       = ws;
    float* overall   = ws + B_ROWS;
    float* pair_part = ws + 2 * B_ROWS;
    float* hub_part  = ws + 2 * B_ROWS + NBLK_B;
    unsigned int* cnt_part = (unsigned int*)(ws + 2 * B_ROWS + 2 * NBLK_B);

    sim_kernel<<<B_ROWS, 256, 0, stream>>>(z_ref, z_perf, tgt, sim, overall);
    pair_kernel<<<NBLK_B, 256, 0, stream>>>(sim, overall, pred, tgt,
                                            pair_part, hub_part, cnt_part);
    finalize_kernel<<<1, 256, 0, stream>>>(hub_part, pair_part, cnt_part, out);
}